// Round 1
// baseline (607.701 us; speedup 1.0000x reference)
//
#include <hip/hip_runtime.h>

// SpatialEncoding: out[b,n1,n2] = weight[path_distance_map[b,e]] for the
// LAST e with edge_index_map[b,e]=(n1,n2); else weight[511].
// Inputs: d_in[0]=x (unused, shape only), d_in[1]=weight (512 f32),
//         d_in[2]=path_distance_map (B*E i32), d_in[3]=edge_index_map (B*E*2 i32).
// Output: B*T*T f32.

#define BB 64
#define TT 1024
#define EE 200000
#define MAXD 512

// Pass 2: last-write-wins via atomicMax of packed (e<<9 | d) into the
// int32-viewed output (pre-initialized to -1 by memset 0xFF).
__global__ void __launch_bounds__(256)
scatter_max_kernel(const int* __restrict__ pdm,
                   const int* __restrict__ eim,
                   int* __restrict__ outi) {
    int e = blockIdx.x * blockDim.x + threadIdx.x;
    int b = blockIdx.y;
    if (e >= EE) return;
    int d = pdm[(size_t)b * EE + e];
    int2 n = ((const int2*)eim)[(size_t)b * EE + e];  // (node1, node2), 8B aligned
    int packed = (e << 9) | d;                        // e<2^18, d<2^9 -> fits, positive
    atomicMax(&outi[((size_t)b * TT + (size_t)n.x) * TT + (size_t)n.y], packed);
}

// Pass 3: decode packed keys -> embedding values, in place.
// v < 0 (never scattered) -> default row 511 (= weight[-1,0]).
__global__ void __launch_bounds__(256)
finalize_kernel(const float* __restrict__ w, float* __restrict__ out, size_t n4) {
    __shared__ float sw[MAXD];
    for (int i = threadIdx.x; i < MAXD; i += blockDim.x) sw[i] = w[i];
    __syncthreads();
    const size_t stride = (size_t)gridDim.x * blockDim.x;
    int4* pi = (int4*)out;
    float4* pf = (float4*)out;
    for (size_t i = (size_t)blockIdx.x * blockDim.x + threadIdx.x; i < n4; i += stride) {
        int4 v = pi[i];
        float4 r;
        r.x = sw[v.x < 0 ? (MAXD - 1) : (v.x & (MAXD - 1))];
        r.y = sw[v.y < 0 ? (MAXD - 1) : (v.y & (MAXD - 1))];
        r.z = sw[v.z < 0 ? (MAXD - 1) : (v.z & (MAXD - 1))];
        r.w = sw[v.w < 0 ? (MAXD - 1) : (v.w & (MAXD - 1))];
        pf[i] = r;
    }
}

extern "C" void kernel_launch(void* const* d_in, const int* in_sizes, int n_in,
                              void* d_out, int out_size, void* d_ws, size_t ws_size,
                              hipStream_t stream) {
    const float* w   = (const float*)d_in[1];
    const int*   pdm = (const int*)d_in[2];
    const int*   eim = (const int*)d_in[3];
    float* out = (float*)d_out;

    // Pass 1: every int32 slot -> 0xFFFFFFFF = -1 (capture-safe async memset).
    hipMemsetAsync(d_out, 0xFF, (size_t)out_size * sizeof(float), stream);

    // Pass 2: packed atomicMax scatter, one thread per (b, e).
    dim3 sgrid((EE + 255) / 256, BB);
    scatter_max_kernel<<<sgrid, 256, 0, stream>>>(pdm, eim, (int*)d_out);

    // Pass 3: decode in place, vectorized 16B per thread-iter.
    size_t n4 = (size_t)out_size / 4;  // 67108864 / 4, exact
    finalize_kernel<<<2048, 256, 0, stream>>>(w, out, n4);
}